// Round 6
// baseline (367.603 us; speedup 1.0000x reference)
//
#include <hip/hip_runtime.h>
#include <hip/hip_bf16.h>

using bf16 = __hip_bfloat16;
typedef __attribute__((ext_vector_type(8))) short short8;
typedef __attribute__((ext_vector_type(4))) float f32x4;
typedef __attribute__((ext_vector_type(4))) unsigned short u16x4;

#define DI __device__ __forceinline__

constexpr int MROWS = 16384;   // B * S
constexpr int EMB   = 1024;    // n_embd
constexpr int HID   = 4096;    // hidden

DI void gload16(const bf16* g, bf16* l) {
  __builtin_amdgcn_global_load_lds((const __attribute__((address_space(1))) void*)g,
                                   (__attribute__((address_space(3))) void*)l,
                                   16, 0, 0);
}

// scale = 2^(e-3), inv = 2^(3-e), e = floor(log2(amax)); clamp keeps both normal.
DI void qparams(float amax, float& scale, float& inv) {
  int eb = (int)((__float_as_uint(amax) >> 23) & 255u);
  eb = eb < 4 ? 4 : eb;
  scale = __uint_as_float((unsigned)(eb - 3) << 23);
  inv   = __uint_as_float((unsigned)(257 - eb) << 23);
}

// Block-quantize 32 f32 elements per thread -> bf16 (exact: 4 significand bits)
__global__ void quant32(const float* __restrict__ in, bf16* __restrict__ out, int nblk) {
  int b = blockIdx.x * blockDim.x + threadIdx.x;
  if (b >= nblk) return;
  const f32x4* p = (const f32x4*)(in + (size_t)b * 32);
  f32x4 v[8];
  float amax = 0.f;
#pragma unroll
  for (int i = 0; i < 8; i++) {
    v[i] = __builtin_nontemporal_load(p + i);
    amax = fmaxf(amax, fmaxf(fmaxf(fabsf(v[i][0]), fabsf(v[i][1])),
                             fmaxf(fabsf(v[i][2]), fabsf(v[i][3]))));
  }
  float scale, inv;
  qparams(amax, scale, inv);
  alignas(16) unsigned short us[32];
#pragma unroll
  for (int i = 0; i < 8; i++)
#pragma unroll
    for (int j = 0; j < 4; j++)
      us[i * 4 + j] = (unsigned short)(__float_as_uint(rintf(v[i][j] * inv) * scale) >> 16);
  short8* o = (short8*)(out + (size_t)b * 32);
#pragma unroll
  for (int i = 0; i < 4; i++) o[i] = *(short8*)(us + i * 8);
}

// Fused GELU(exact erf) + 32-block quant + bf16 cast. h already includes bias.
// 32-block spans 8 consecutive lanes (4 elems/lane), reduce via shfl_xor.
__global__ void gelu_quant(const float* __restrict__ h, bf16* __restrict__ out, int n4) {
  const int stride = gridDim.x * blockDim.x;
  for (int i = blockIdx.x * blockDim.x + threadIdx.x; i < n4; i += stride) {
    f32x4 v = __builtin_nontemporal_load((const f32x4*)h + i);
    float g[4];
#pragma unroll
    for (int j = 0; j < 4; j++)
      g[j] = 0.5f * v[j] * (1.0f + erff(v[j] * 0.70710678118654752f));
    float am = fmaxf(fmaxf(fabsf(g[0]), fabsf(g[1])), fmaxf(fabsf(g[2]), fabsf(g[3])));
    am = fmaxf(am, __shfl_xor(am, 1, 64));
    am = fmaxf(am, __shfl_xor(am, 2, 64));
    am = fmaxf(am, __shfl_xor(am, 4, 64));
    float sc, iv;
    qparams(am, sc, iv);
    u16x4 u;
#pragma unroll
    for (int j = 0; j < 4; j++)
      u[j] = (unsigned short)(__float_as_uint(rintf(g[j] * iv) * sc) >> 16);
    *(u16x4*)((unsigned short*)out + (size_t)i * 4) = u;
  }
}

#define MFMA16(a, b, c) __builtin_amdgcn_mfma_f32_16x16x32_bf16(a, b, c, 0, 0, 0)
#define SBAR()    __builtin_amdgcn_s_barrier()
#define WAITVM(n) asm volatile("s_waitcnt vmcnt(" #n ")" ::: "memory")

// Quadrant MFMA cluster (16 MFMA) wrapped in setprio
#define Q_MFMA(MB, NB, BG) \
  __builtin_amdgcn_s_setprio(1); \
  _Pragma("unroll") for (int kk = 0; kk < 2; kk++) \
  _Pragma("unroll") for (int mi = 0; mi < 4; mi++) \
  _Pragma("unroll") for (int ni = 0; ni < 2; ni++) \
    acc[(MB) + mi][(NB) + ni] = MFMA16(af[mi * 2 + kk], BG[ni * 2 + kk], acc[(MB) + mi][(NB) + ni]); \
  __builtin_amdgcn_s_setprio(0);

#define RD_AF(mh) \
  _Pragma("unroll") for (int mi = 0; mi < 4; mi++) { \
    af[mi * 2]     = ldA(db, mh, mi, 0); \
    af[mi * 2 + 1] = ldA(db, mh, mi, 1); }

#define RD_B(half, dst) \
  _Pragma("unroll") for (int ni = 0; ni < 2; ni++) { \
    dst[ni * 2]     = ldB(db, half, ni, 0); \
    dst[ni * 2 + 1] = ldB(db, half, ni, 1); }

// C = A[M x Kd] * Bw[Nd x Kd]^T, 256x256 tile, BK=64, 8 waves (2M x 4N).
// ONE barrier + ONE counted vmcnt(6) per K-tile; stage stream ~1.5-2 tiles
// ahead; XOR-swizzled LDS. GQ=true: fused gelu+quant epilogue (fallback path).
// GQ=false: bias + nontemporal f32 store.
template<int Kd, int Nd, bool GQ>
__global__ void __launch_bounds__(512, 2)
gemm8(const bf16* __restrict__ Ap, const bf16* __restrict__ Bp,
      const float* __restrict__ bias, void* __restrict__ Cout) {
  __shared__ alignas(16) bf16 SH[65536];          // 128 KiB
  bf16* Abuf = SH;                                 // [2 dbuf][2 half][8192]
  bf16* Bbuf = SH + 32768;

  const int tid  = threadIdx.x;
  const int lane = tid & 63, wave = tid >> 6;
  const int l16  = lane & 15, lhi = lane >> 4;
  const int wr   = wave >> 2, wc  = wave & 3;

  // XCD-chunked, brow-fast ordering (8 brow per XCD chunk)
  const int idx  = blockIdx.x >> 3;
  const int xid  = blockIdx.x & 7;
  const int brow = (xid * 8 + (idx & 7)) * 256;
  const int bcol = (idx >> 3) * 256;

  // staging: linear LDS dest, inverse-swizzled global source
  const int r0 = tid >> 3;
  const int sl = (tid & 7) ^ (r0 & 7);
  const bf16* asrc = Ap + (size_t)(brow + r0) * Kd + sl * 8;
  const bf16* bsrc = Bp + (size_t)(bcol + r0) * Kd + sl * 8;

  auto stA = [&](int tt, int half) {
    const bf16* s = asrc + (size_t)half * 128 * Kd + tt * 64;
    bf16* d = Abuf + ((tt & 1) * 2 + half) * 8192 + tid * 8;
    gload16(s, d); gload16(s + (size_t)64 * Kd, d + 4096);
  };
  auto stB = [&](int tt, int half) {
    const bf16* s = bsrc + (size_t)half * 128 * Kd + tt * 64;
    bf16* d = Bbuf + ((tt & 1) * 2 + half) * 8192 + tid * 8;
    gload16(s, d); gload16(s + (size_t)64 * Kd, d + 4096);
  };

  const int sx = l16 & 7;
  const int arow = wr * 16 + l16;
  auto ldA = [&](int db, int mh, int mi, int kk) -> short8 {
    return *(const short8*)(Abuf + (db * 2 + mh) * 8192 +
                            (mi * 32 + arow) * 64 + ((kk * 4 + lhi) ^ sx) * 8);
  };
  const int brl = wc * 32 + l16;
  auto ldB = [&](int db, int half, int ni, int kk) -> short8 {
    return *(const short8*)(Bbuf + (db * 2 + half) * 8192 +
                            (brl + ni * 16) * 64 + ((kk * 4 + lhi) ^ sx) * 8);
  };

  f32x4 acc[8][4] = {};
  short8 af[8], bgl[4], bgh[4];

  constexpr int NT = Kd / 64;                      // >= 3 for our shapes

  // prologue: tile 0 complete (8 gloads) + {A_lo,B_lo,B_hi}(1) (6 gloads)
  stA(0, 0); stB(0, 0); stB(0, 1); stA(0, 1);
  stA(1, 0); stB(1, 0); stB(1, 1);
  WAITVM(6); SBAR();

  for (int t = 0; t <= NT - 3; ++t) {
    const int db = t & 1;
    RD_AF(0) RD_B(0, bgl) RD_B(1, bgh)
    stA(t + 1, 1);
    Q_MFMA(0, 0, bgl)
    stA(t + 2, 0);
    Q_MFMA(0, 2, bgh)
    stB(t + 2, 0);
    RD_AF(1)
    stB(t + 2, 1);
    Q_MFMA(4, 0, bgl)
    Q_MFMA(4, 2, bgh)
    WAITVM(6); SBAR();
  }

  // peel t = NT-2
  {
    const int db = (NT - 2) & 1;
    RD_AF(0) RD_B(0, bgl) RD_B(1, bgh)
    stA(NT - 1, 1);
    Q_MFMA(0, 0, bgl)
    Q_MFMA(0, 2, bgh)
    RD_AF(1)
    Q_MFMA(4, 0, bgl)
    Q_MFMA(4, 2, bgh)
    WAITVM(0); SBAR();
  }

  // tail t = NT-1
  {
    const int db = (NT - 1) & 1;
    RD_AF(0) RD_B(0, bgl) RD_B(1, bgh)
    Q_MFMA(0, 0, bgl)
    Q_MFMA(0, 2, bgh)
    RD_AF(1)
    Q_MFMA(4, 0, bgl)
    Q_MFMA(4, 2, bgh)
  }

  // ---- epilogue ----
  const int cb = bcol + wc * 32;
  float bv[4];
#pragma unroll
  for (int n = 0; n < 4; n++) bv[n] = bias[cb + (n >> 1) * 128 + (n & 1) * 16 + l16];

  if constexpr (GQ) {
    SBAR();
#pragma unroll
    for (int m = 0; m < 8; m++) {
      const int rl0 = m * 32 + wr * 16 + lhi * 4;
#pragma unroll
      for (int r = 0; r < 4; r++) {
        float g[4];
#pragma unroll
        for (int n = 0; n < 4; n++) {
          float v = acc[m][n][r] + bv[n];
          g[n] = 0.5f * v * (1.0f + erff(v * 0.70710678118654752f));
        }
#pragma unroll
        for (int p = 0; p < 2; p++) {
          float am = fmaxf(fabsf(g[p * 2]), fabsf(g[p * 2 + 1]));
#pragma unroll
          for (int msk = 1; msk <= 8; msk <<= 1) am = fmaxf(am, __shfl_xor(am, msk, 64));
          float sc, iv; qparams(am, sc, iv);
          const int rowb = (rl0 + r) * 256;
          const int c0   = wc * 32 + p * 128;
          SH[rowb + ((c0 + l16)      ^ (lhi << 3))] = __float2bfloat16(rintf(g[p * 2]     * iv) * sc);
          SH[rowb + ((c0 + 16 + l16) ^ (lhi << 3))] = __float2bfloat16(rintf(g[p * 2 + 1] * iv) * sc);
        }
      }
    }
    SBAR();
    bf16* outp = (bf16*)Cout;
#pragma unroll
    for (int i = 0; i < 16; i++) {
      const int c   = i * 512 + tid;
      const int row = c >> 5, cc = c & 31;
      const int scc = cc ^ ((row >> 2) & 3);
      *(short8*)(outp + (size_t)(brow + row) * Nd + bcol + cc * 8) =
          *(const short8*)(SH + (size_t)row * 256 + scc * 8);
    }
  } else {
    float* outp = (float*)Cout;
#pragma unroll
    for (int m = 0; m < 8; m++) {
      const size_t rbase = (size_t)(brow + m * 32 + wr * 16 + lhi * 4);
#pragma unroll
      for (int r = 0; r < 4; r++) {
        const size_t ro = (rbase + r) * Nd;
#pragma unroll
        for (int n = 0; n < 4; n++)
          __builtin_nontemporal_store(acc[m][n][r] + bv[n],
              &outp[ro + cb + (n >> 1) * 128 + (n & 1) * 16 + l16]);
      }
    }
  }
}

extern "C" void kernel_launch(void* const* d_in, const int* in_sizes, int n_in,
                              void* d_out, int out_size, void* d_ws, size_t ws_size,
                              hipStream_t stream) {
  const float* x      = (const float*)d_in[0];
  const float* w_fc   = (const float*)d_in[1];
  const float* b_fc   = (const float*)d_in[2];
  const float* w_proj = (const float*)d_in[3];
  const float* b_proj = (const float*)d_in[4];

  char* base = (char*)d_ws;
  const size_t MB = 1u << 20;

  if (ws_size >= 392 * MB) {
    // Split path. Layout: [wpq 8MB][hq 128MB (xq@+0, wfq@+32MB alias)][h 256MB]
    bf16*  wpq = (bf16*)(base);
    bf16*  xq  = (bf16*)(base + 8 * MB);
    bf16*  wfq = (bf16*)(base + 40 * MB);
    bf16*  hq  = (bf16*)(base + 8 * MB);          // clobbers xq/wfq after GEMM1
    float* h   = (float*)(base + 136 * MB);

    quant32<<<(MROWS * EMB / 32 + 255) / 256, 256, 0, stream>>>(x, xq, MROWS * EMB / 32);
    quant32<<<(HID * EMB / 32 + 255) / 256, 256, 0, stream>>>(w_fc, wfq, HID * EMB / 32);
    quant32<<<(EMB * HID / 32 + 255) / 256, 256, 0, stream>>>(w_proj, wpq, EMB * HID / 32);

    gemm8<EMB, HID, false><<<(MROWS / 256) * (HID / 256), 512, 0, stream>>>(xq, wfq, b_fc, h);
    gelu_quant<<<2048, 256, 0, stream>>>(h, hq, MROWS * HID / 4);
    gemm8<HID, EMB, false><<<(MROWS / 256) * (EMB / 256), 512, 0, stream>>>(hq, wpq, b_proj, (float*)d_out);
  } else {
    // Fallback: R4 fused path (176 MB)
    char* ws = base;
    bf16* xq  = (bf16*)ws;  ws += (size_t)MROWS * EMB * 2;
    bf16* wfq = (bf16*)ws;  ws += (size_t)HID * EMB * 2;
    bf16* wpq = (bf16*)ws;  ws += (size_t)EMB * HID * 2;
    bf16* hq  = (bf16*)ws;

    quant32<<<(MROWS * EMB / 32 + 255) / 256, 256, 0, stream>>>(x, xq, MROWS * EMB / 32);
    quant32<<<(HID * EMB / 32 + 255) / 256, 256, 0, stream>>>(w_fc, wfq, HID * EMB / 32);
    quant32<<<(EMB * HID / 32 + 255) / 256, 256, 0, stream>>>(w_proj, wpq, EMB * HID / 32);

    gemm8<EMB, HID, true ><<<(MROWS / 256) * (HID / 256), 512, 0, stream>>>(xq, wfq, b_fc, hq);
    gemm8<HID, EMB, false><<<(MROWS / 256) * (EMB / 256), 512, 0, stream>>>(hq, wpq, b_proj, (float*)d_out);
  }
}

// Round 7
// 335.376 us; speedup vs baseline: 1.0961x; 1.0961x over previous
//
#include <hip/hip_runtime.h>
#include <hip/hip_bf16.h>

using bf16 = __hip_bfloat16;
typedef __attribute__((ext_vector_type(8))) short short8;
typedef __attribute__((ext_vector_type(4))) float f32x4;

#define DI __device__ __forceinline__

constexpr int MROWS = 16384;   // B * S
constexpr int EMB   = 1024;    // n_embd
constexpr int HID   = 4096;    // hidden

DI void gload16(const bf16* g, bf16* l) {
  __builtin_amdgcn_global_load_lds((const __attribute__((address_space(1))) void*)g,
                                   (__attribute__((address_space(3))) void*)l,
                                   16, 0, 0);
}

// scale = 2^(e-3), inv = 2^(3-e), e = floor(log2(amax)); clamp keeps both normal.
DI void qparams(float amax, float& scale, float& inv) {
  int eb = (int)((__float_as_uint(amax) >> 23) & 255u);
  eb = eb < 4 ? 4 : eb;
  scale = __uint_as_float((unsigned)(eb - 3) << 23);
  inv   = __uint_as_float((unsigned)(257 - eb) << 23);
}

// Block-quantize 32 f32 elements per thread -> bf16 (exact: 4 significand bits)
__global__ void quant32(const float* __restrict__ in, bf16* __restrict__ out, int nblk) {
  int b = blockIdx.x * blockDim.x + threadIdx.x;
  if (b >= nblk) return;
  const f32x4* p = (const f32x4*)(in + (size_t)b * 32);
  f32x4 v[8];
  float amax = 0.f;
#pragma unroll
  for (int i = 0; i < 8; i++) {
    v[i] = p[i];
    amax = fmaxf(amax, fmaxf(fmaxf(fabsf(v[i][0]), fabsf(v[i][1])),
                             fmaxf(fabsf(v[i][2]), fabsf(v[i][3]))));
  }
  float scale, inv;
  qparams(amax, scale, inv);
  alignas(16) unsigned short us[32];
#pragma unroll
  for (int i = 0; i < 8; i++)
#pragma unroll
    for (int j = 0; j < 4; j++)
      us[i * 4 + j] = (unsigned short)(__float_as_uint(rintf(v[i][j] * inv) * scale) >> 16);
  short8* o = (short8*)(out + (size_t)b * 32);
#pragma unroll
  for (int i = 0; i < 4; i++) o[i] = *(short8*)(us + i * 8);
}

#define MFMA16(a, b, c) __builtin_amdgcn_mfma_f32_16x16x32_bf16(a, b, c, 0, 0, 0)
#define SBAR()    __builtin_amdgcn_s_barrier()
#define WAITVM(n) asm volatile("s_waitcnt vmcnt(" #n ")" ::: "memory")

// 16-lane (l16-group) fmax reduce, pure VALU via DPP (no DS-pipe traffic).
// quad_perm[1,0,3,2]=0xB1, quad_perm[2,3,0,1]=0x4E, row_ror:4=0x124, row_ror:8=0x128
#define DPPMAX(x, ctrl) \
  x = fmaxf(x, __int_as_float(__builtin_amdgcn_update_dpp( \
          0, __float_as_int(x), ctrl, 0xf, 0xf, false)));
DI float redmax16(float x) {
  DPPMAX(x, 0xB1) DPPMAX(x, 0x4E) DPPMAX(x, 0x124) DPPMAX(x, 0x128)
  return x;
}

// Quadrant MFMA cluster (16 MFMA) wrapped in setprio
#define Q_MFMA(MB, NB, BG) \
  __builtin_amdgcn_s_setprio(1); \
  _Pragma("unroll") for (int kk = 0; kk < 2; kk++) \
  _Pragma("unroll") for (int mi = 0; mi < 4; mi++) \
  _Pragma("unroll") for (int ni = 0; ni < 2; ni++) \
    acc[(MB) + mi][(NB) + ni] = MFMA16(af[mi * 2 + kk], BG[ni * 2 + kk], acc[(MB) + mi][(NB) + ni]); \
  __builtin_amdgcn_s_setprio(0);

#define RD_AF(mh) \
  _Pragma("unroll") for (int mi = 0; mi < 4; mi++) { \
    af[mi * 2]     = ldA(db, mh, mi, 0); \
    af[mi * 2 + 1] = ldA(db, mh, mi, 1); }

#define RD_B(half, dst) \
  _Pragma("unroll") for (int ni = 0; ni < 2; ni++) { \
    dst[ni * 2]     = ldB(db, half, ni, 0); \
    dst[ni * 2 + 1] = ldB(db, half, ni, 1); }

// C = A[M x Kd] * Bw[Nd x Kd]^T, 256x256 tile, BK=64, 8 waves (2M x 4N).
// ONE barrier + ONE counted vmcnt(6) per K-tile; stage stream ~2 tiles ahead;
// XOR-swizzled LDS. GQ=true: fused bias+GELU+quant epilogue with DPP amax
// reduce and conflict-free LDS restage; GQ=false: bias + nt f32 store.
template<int Kd, int Nd, bool GQ>
__global__ void __launch_bounds__(512, 2)
gemm8(const bf16* __restrict__ Ap, const bf16* __restrict__ Bp,
      const float* __restrict__ bias, void* __restrict__ Cout) {
  __shared__ alignas(16) bf16 SH[65536];          // 128 KiB
  bf16* Abuf = SH;                                 // [2 dbuf][2 half][8192]
  bf16* Bbuf = SH + 32768;

  const int tid  = threadIdx.x;
  const int lane = tid & 63, wave = tid >> 6;
  const int l16  = lane & 15, lhi = lane >> 4;
  const int wr   = wave >> 2, wc  = wave & 3;

  // XCD-chunked, brow-fast ordering (8 brow per XCD chunk)
  const int idx  = blockIdx.x >> 3;
  const int xid  = blockIdx.x & 7;
  const int brow = (xid * 8 + (idx & 7)) * 256;
  const int bcol = (idx >> 3) * 256;

  // staging: linear LDS dest, inverse-swizzled global source
  const int r0 = tid >> 3;
  const int sl = (tid & 7) ^ (r0 & 7);
  const bf16* asrc = Ap + (size_t)(brow + r0) * Kd + sl * 8;
  const bf16* bsrc = Bp + (size_t)(bcol + r0) * Kd + sl * 8;

  auto stA = [&](int tt, int half) {
    const bf16* s = asrc + (size_t)half * 128 * Kd + tt * 64;
    bf16* d = Abuf + ((tt & 1) * 2 + half) * 8192 + tid * 8;
    gload16(s, d); gload16(s + (size_t)64 * Kd, d + 4096);
  };
  auto stB = [&](int tt, int half) {
    const bf16* s = bsrc + (size_t)half * 128 * Kd + tt * 64;
    bf16* d = Bbuf + ((tt & 1) * 2 + half) * 8192 + tid * 8;
    gload16(s, d); gload16(s + (size_t)64 * Kd, d + 4096);
  };

  const int sx = l16 & 7;
  const int arow = wr * 16 + l16;
  auto ldA = [&](int db, int mh, int mi, int kk) -> short8 {
    return *(const short8*)(Abuf + (db * 2 + mh) * 8192 +
                            (mi * 32 + arow) * 64 + ((kk * 4 + lhi) ^ sx) * 8);
  };
  const int brl = wc * 32 + l16;
  auto ldB = [&](int db, int half, int ni, int kk) -> short8 {
    return *(const short8*)(Bbuf + (db * 2 + half) * 8192 +
                            (brl + ni * 16) * 64 + ((kk * 4 + lhi) ^ sx) * 8);
  };

  f32x4 acc[8][4] = {};
  short8 af[8], bgl[4], bgh[4];

  constexpr int NT = Kd / 64;                      // >= 3 for our shapes

  // prologue: tile 0 complete (8 gloads) + {A_lo,B_lo,B_hi}(1) (6 gloads)
  stA(0, 0); stB(0, 0); stB(0, 1); stA(0, 1);
  stA(1, 0); stB(1, 0); stB(1, 1);
  WAITVM(6); SBAR();

  for (int t = 0; t <= NT - 3; ++t) {
    const int db = t & 1;
    RD_AF(0) RD_B(0, bgl) RD_B(1, bgh)
    stA(t + 1, 1);
    Q_MFMA(0, 0, bgl)
    stA(t + 2, 0);
    Q_MFMA(0, 2, bgh)
    stB(t + 2, 0);
    RD_AF(1)
    stB(t + 2, 1);
    Q_MFMA(4, 0, bgl)
    Q_MFMA(4, 2, bgh)
    WAITVM(6); SBAR();
  }

  // peel t = NT-2
  {
    const int db = (NT - 2) & 1;
    RD_AF(0) RD_B(0, bgl) RD_B(1, bgh)
    stA(NT - 1, 1);
    Q_MFMA(0, 0, bgl)
    Q_MFMA(0, 2, bgh)
    RD_AF(1)
    Q_MFMA(4, 0, bgl)
    Q_MFMA(4, 2, bgh)
    WAITVM(0); SBAR();
  }

  // tail t = NT-1
  {
    const int db = (NT - 1) & 1;
    RD_AF(0) RD_B(0, bgl) RD_B(1, bgh)
    Q_MFMA(0, 0, bgl)
    Q_MFMA(0, 2, bgh)
    RD_AF(1)
    Q_MFMA(4, 0, bgl)
    Q_MFMA(4, 2, bgh)
  }

  // ---- epilogue ----
  const int cb = bcol + wc * 32;
  float bv[4];
#pragma unroll
  for (int n = 0; n < 4; n++) bv[n] = bias[cb + (n >> 1) * 128 + (n & 1) * 16 + l16];

  if constexpr (GQ) {
    bf16* outp = (bf16*)Cout;
    // Two half-passes (rows mh2*128..+127) through SH[128][256] halfwords.
    // Write swizzle: col' = col ^ (lhi<<4)  -> 4 lhi-groups hit disjoint bank
    // octets (conflict-free). Read unswizzle at 16B-chunk level: cc ^ (lhi<<1).
#pragma unroll
    for (int mh2 = 0; mh2 < 2; mh2++) {
      __syncthreads();                             // LDS free / prev reads done
#pragma unroll
      for (int mm = 0; mm < 4; mm++) {
        const int m = mh2 * 4 + mm;
        const int rl0 = mm * 32 + wr * 16 + lhi * 4;   // row within half
#pragma unroll
        for (int r = 0; r < 4; r++) {
          float g[4];
#pragma unroll
          for (int n = 0; n < 4; n++) {
            float v = acc[m][n][r] + bv[n];
            g[n] = 0.5f * v * (1.0f + erff(v * 0.70710678118654752f));
          }
          const int rowb = (rl0 + r) * 256;
#pragma unroll
          for (int p = 0; p < 2; p++) {
            float am = redmax16(fmaxf(fabsf(g[p * 2]), fabsf(g[p * 2 + 1])));
            float sc, iv; qparams(am, sc, iv);
            const int c0 = wc * 32 + p * 128;
            SH[rowb + ((c0 + l16)      ^ (lhi << 4))] = __float2bfloat16(rintf(g[p * 2]     * iv) * sc);
            SH[rowb + ((c0 + 16 + l16) ^ (lhi << 4))] = __float2bfloat16(rintf(g[p * 2 + 1] * iv) * sc);
          }
        }
      }
      __syncthreads();
#pragma unroll
      for (int i = 0; i < 8; i++) {
        const int c   = i * 512 + tid;             // 16B chunk id within half
        const int row = c >> 5, cc = c & 31;
        const int scc = cc ^ (((row >> 2) & 3) << 1);
        *(short8*)(outp + (size_t)(brow + mh2 * 128 + row) * Nd + bcol + cc * 8) =
            *(const short8*)(SH + (size_t)row * 256 + scc * 8);
      }
    }
  } else {
    float* outp = (float*)Cout;
#pragma unroll
    for (int m = 0; m < 8; m++) {
      const size_t rbase = (size_t)(brow + m * 32 + wr * 16 + lhi * 4);
#pragma unroll
      for (int r = 0; r < 4; r++) {
        const size_t ro = (rbase + r) * Nd;
#pragma unroll
        for (int n = 0; n < 4; n++)
          __builtin_nontemporal_store(acc[m][n][r] + bv[n],
              &outp[ro + cb + (n >> 1) * 128 + (n & 1) * 16 + l16]);
      }
    }
  }
}

extern "C" void kernel_launch(void* const* d_in, const int* in_sizes, int n_in,
                              void* d_out, int out_size, void* d_ws, size_t ws_size,
                              hipStream_t stream) {
  const float* x      = (const float*)d_in[0];
  const float* w_fc   = (const float*)d_in[1];
  const float* b_fc   = (const float*)d_in[2];
  const float* w_proj = (const float*)d_in[3];
  const float* b_proj = (const float*)d_in[4];

  char* ws = (char*)d_ws;
  bf16* xq  = (bf16*)ws;  ws += (size_t)MROWS * EMB * 2;   // 32 MB
  bf16* wfq = (bf16*)ws;  ws += (size_t)HID * EMB * 2;     //  8 MB
  bf16* wpq = (bf16*)ws;  ws += (size_t)EMB * HID * 2;     //  8 MB
  bf16* hq  = (bf16*)ws;                                   // 128 MB

  quant32<<<(MROWS * EMB / 32 + 255) / 256, 256, 0, stream>>>(x, xq, MROWS * EMB / 32);
  quant32<<<(HID * EMB / 32 + 255) / 256, 256, 0, stream>>>(w_fc, wfq, HID * EMB / 32);
  quant32<<<(EMB * HID / 32 + 255) / 256, 256, 0, stream>>>(w_proj, wpq, EMB * HID / 32);

  gemm8<EMB, HID, true ><<<(MROWS / 256) * (HID / 256), 512, 0, stream>>>(xq, wfq, b_fc, hq);
  gemm8<HID, EMB, false><<<(MROWS / 256) * (EMB / 256), 512, 0, stream>>>(hq, wpq, b_proj, (float*)d_out);
}

// Round 8
// 331.662 us; speedup vs baseline: 1.1084x; 1.0112x over previous
//
#include <hip/hip_runtime.h>
#include <hip/hip_bf16.h>

using bf16 = __hip_bfloat16;
typedef __attribute__((ext_vector_type(8))) short short8;
typedef __attribute__((ext_vector_type(4))) float f32x4;

#define DI __device__ __forceinline__

constexpr int MROWS = 16384;   // B * S
constexpr int EMB   = 1024;    // n_embd
constexpr int HID   = 4096;    // hidden

DI void gload16(const bf16* g, bf16* l) {
  __builtin_amdgcn_global_load_lds((const __attribute__((address_space(1))) void*)g,
                                   (__attribute__((address_space(3))) void*)l,
                                   16, 0, 0);
}

// scale = 2^(e-3), inv = 2^(3-e), e = floor(log2(amax)); clamp keeps both normal.
DI void qparams(float amax, float& scale, float& inv) {
  int eb = (int)((__float_as_uint(amax) >> 23) & 255u);
  eb = eb < 4 ? 4 : eb;
  scale = __uint_as_float((unsigned)(eb - 3) << 23);
  inv   = __uint_as_float((unsigned)(257 - eb) << 23);
}

// Block-quantize 32 f32 elements per thread -> bf16 (exact: 4 significand bits)
__global__ void quant32(const float* __restrict__ in, bf16* __restrict__ out, int nblk) {
  int b = blockIdx.x * blockDim.x + threadIdx.x;
  if (b >= nblk) return;
  const f32x4* p = (const f32x4*)(in + (size_t)b * 32);
  f32x4 v[8];
  float amax = 0.f;
#pragma unroll
  for (int i = 0; i < 8; i++) {
    v[i] = p[i];
    amax = fmaxf(amax, fmaxf(fmaxf(fabsf(v[i][0]), fabsf(v[i][1])),
                             fmaxf(fabsf(v[i][2]), fabsf(v[i][3]))));
  }
  float scale, inv;
  qparams(amax, scale, inv);
  alignas(16) unsigned short us[32];
#pragma unroll
  for (int i = 0; i < 8; i++)
#pragma unroll
    for (int j = 0; j < 4; j++)
      us[i * 4 + j] = (unsigned short)(__float_as_uint(rintf(v[i][j] * inv) * scale) >> 16);
  short8* o = (short8*)(out + (size_t)b * 32);
#pragma unroll
  for (int i = 0; i < 4; i++) o[i] = *(short8*)(us + i * 8);
}

#define MFMA16(a, b, c) __builtin_amdgcn_mfma_f32_16x16x32_bf16(a, b, c, 0, 0, 0)
#define SBAR()    __builtin_amdgcn_s_barrier()
#define WAITVM(n) asm volatile("s_waitcnt vmcnt(" #n ")" ::: "memory")

// 16-lane (l16-group) fmax reduce, pure VALU via DPP.
#define DPPMAX(x, ctrl) \
  x = fmaxf(x, __int_as_float(__builtin_amdgcn_update_dpp( \
          0, __float_as_int(x), ctrl, 0xf, 0xf, false)));
DI float redmax16(float x) {
  DPPMAX(x, 0xB1) DPPMAX(x, 0x4E) DPPMAX(x, 0x124) DPPMAX(x, 0x128)
  return x;
}

#define Q_MFMA(MB, NB, BG) \
  __builtin_amdgcn_s_setprio(1); \
  _Pragma("unroll") for (int kk = 0; kk < 2; kk++) \
  _Pragma("unroll") for (int mi = 0; mi < 4; mi++) \
  _Pragma("unroll") for (int ni = 0; ni < 2; ni++) \
    acc[(MB) + mi][(NB) + ni] = MFMA16(af[mi * 2 + kk], BG[ni * 2 + kk], acc[(MB) + mi][(NB) + ni]); \
  __builtin_amdgcn_s_setprio(0);

#define RD_AF(mh) \
  _Pragma("unroll") for (int mi = 0; mi < 4; mi++) { \
    af[mi * 2]     = ldA(db, mh, mi, 0); \
    af[mi * 2 + 1] = ldA(db, mh, mi, 1); }

#define RD_B(half, dst) \
  _Pragma("unroll") for (int ni = 0; ni < 2; ni++) { \
    dst[ni * 2]     = ldB(db, half, ni, 0); \
    dst[ni * 2 + 1] = ldB(db, half, ni, 1); }

// C = A[M x Kd] * Bw[Nd x Kd]^T, 256x256 tile, BK=64, 8 waves (2M x 4N).
// ONE barrier + ONE counted vmcnt(6) per K-tile. OT=2 (GEMM1): each block does
// two output tiles (brow, brow+8192) with spliced pipelines — segment-B's
// first K-tiles stage during segment-A's last tiles, and epilogue-A's
// erf/quant burst overlaps those in-flight loads.
template<int Kd, int Nd, bool GQ, int OT>
__global__ void __launch_bounds__(512, 2)
gemm8(const bf16* __restrict__ Ap, const bf16* __restrict__ Bp,
      const float* __restrict__ bias, void* __restrict__ Cout) {
  __shared__ alignas(16) bf16 SH[65536];          // 128 KiB staging only
  bf16* Abuf = SH;                                 // [2 dbuf][2 half][8192]
  bf16* Bbuf = SH + 32768;

  const int tid  = threadIdx.x;
  const int lane = tid & 63, wave = tid >> 6;
  const int l16  = lane & 15, lhi = lane >> 4;
  const int wr   = wave >> 2, wc  = wave & 3;

  int brow, bcol;
  const int idx = blockIdx.x >> 3, xid = blockIdx.x & 7;
  if constexpr (OT == 2) { brow = (xid * 4 + (idx & 3)) * 256; bcol = (idx >> 2) * 256; }
  else                   { brow = (xid * 8 + (idx & 7)) * 256; bcol = (idx >> 3) * 256; }

  const int r0 = tid >> 3;
  const int sl = (tid & 7) ^ (r0 & 7);
  const bf16* asrc = Ap + (size_t)(brow + r0) * Kd + sl * 8;
  const bf16* bsrc = Bp + (size_t)(bcol + r0) * Kd + sl * 8;

  auto stA = [&](int tt, int half) {
    const bf16* s = asrc + (size_t)half * 128 * Kd + tt * 64;
    bf16* d = Abuf + ((tt & 1) * 2 + half) * 8192 + tid * 8;
    gload16(s, d); gload16(s + (size_t)64 * Kd, d + 4096);
  };
  auto stB = [&](int tt, int half) {
    const bf16* s = bsrc + (size_t)half * 128 * Kd + tt * 64;
    bf16* d = Bbuf + ((tt & 1) * 2 + half) * 8192 + tid * 8;
    gload16(s, d); gload16(s + (size_t)64 * Kd, d + 4096);
  };

  const int sx = l16 & 7;
  const int arow = wr * 16 + l16;
  auto ldA = [&](int db, int mh, int mi, int kk) -> short8 {
    return *(const short8*)(Abuf + (db * 2 + mh) * 8192 +
                            (mi * 32 + arow) * 64 + ((kk * 4 + lhi) ^ sx) * 8);
  };
  const int brl = wc * 32 + l16;
  auto ldB = [&](int db, int half, int ni, int kk) -> short8 {
    return *(const short8*)(Bbuf + (db * 2 + half) * 8192 +
                            (brl + ni * 16) * 64 + ((kk * 4 + lhi) ^ sx) * 8);
  };

  f32x4 acc[8][4] = {};
  short8 af[8], bgl[4], bgh[4];

  constexpr int NT = Kd / 64;                      // 16 (GEMM1) / 64 (GEMM2)

  const int cb = bcol + wc * 32;
  float bv[4];
#pragma unroll
  for (int n = 0; n < 4; n++) bv[n] = bias[cb + (n >> 1) * 128 + (n & 1) * 16 + l16];

  // GQ epilogue: bias+GELU+blockquant, direct nontemporal 2B stores (no LDS).
  auto epiGQ = [&](int browseg) {
    unsigned short* outp = (unsigned short*)Cout;
#pragma unroll
    for (int m = 0; m < 8; m++) {
#pragma unroll
      for (int r = 0; r < 4; r++) {
        float g[4];
#pragma unroll
        for (int n = 0; n < 4; n++) {
          float v = acc[m][n][r] + bv[n];
          g[n] = 0.5f * v * (1.0f + erff(v * 0.70710678118654752f));
        }
        const size_t ro = (size_t)(browseg + m * 32 + wr * 16 + lhi * 4 + r) * Nd;
#pragma unroll
        for (int p = 0; p < 2; p++) {
          float am = redmax16(fmaxf(fabsf(g[p * 2]), fabsf(g[p * 2 + 1])));
          float sc, iv; qparams(am, sc, iv);
          unsigned short* o = outp + ro + cb + p * 128 + l16;
          __builtin_nontemporal_store(
              (unsigned short)(__float_as_uint(rintf(g[p * 2] * iv) * sc) >> 16), o);
          __builtin_nontemporal_store(
              (unsigned short)(__float_as_uint(rintf(g[p * 2 + 1] * iv) * sc) >> 16), o + 16);
        }
      }
    }
  };

  auto main_iter = [&](int t) {
    const int db = t & 1;
    RD_AF(0) RD_B(0, bgl) RD_B(1, bgh)
    stA(t + 1, 1);
    Q_MFMA(0, 0, bgl)
    stA(t + 2, 0);
    Q_MFMA(0, 2, bgh)
    stB(t + 2, 0);
    RD_AF(1)
    stB(t + 2, 1);
    Q_MFMA(4, 0, bgl)
    Q_MFMA(4, 2, bgh)
    WAITVM(6); SBAR();
  };

  // ---- prologue: tile 0 complete + {A_lo,B_lo,B_hi}(1) ----
  stA(0, 0); stB(0, 0); stB(0, 1); stA(0, 1);
  stA(1, 0); stB(1, 0); stB(1, 1);
  WAITVM(6); SBAR();

  for (int t = 0; t <= NT - 3; ++t) main_iter(t);

  // peel t = NT-2: stage A_hi(NT-1); full drain
  {
    const int db = (NT - 2) & 1;
    RD_AF(0) RD_B(0, bgl) RD_B(1, bgh)
    stA(NT - 1, 1);
    Q_MFMA(0, 0, bgl)
    Q_MFMA(0, 2, bgh)
    RD_AF(1)
    Q_MFMA(4, 0, bgl)
    Q_MFMA(4, 2, bgh)
    WAITVM(0); SBAR();
  }

  if constexpr (OT == 2) {
    // tail t = NT-1 with segment-B tile-0 staging (buf0 freed at peel's SBAR)
    asrc += (size_t)8192 * Kd;                    // advance to brow+8192
    {
      const int db = (NT - 1) & 1;
      stA(0, 0); stB(0, 0); stB(0, 1); stA(0, 1); // 8 loads -> buf0
      RD_AF(0) RD_B(0, bgl) RD_B(1, bgh)
      Q_MFMA(0, 0, bgl)
      Q_MFMA(0, 2, bgh)
      RD_AF(1)
      Q_MFMA(4, 0, bgl)
      Q_MFMA(4, 2, bgh)
      SBAR();                                     // all waves done reading buf1
    }
    epiGQ(brow);                                  // erf burst overlaps 8 in-flight loads
    stA(1, 0); stB(1, 0); stB(1, 1);              // 6 loads -> buf1 (after stores!)
    WAITVM(6); SBAR();                            // drain stores + tile-0 loads
#pragma unroll
    for (int m = 0; m < 8; m++)
#pragma unroll
      for (int n = 0; n < 4; n++) acc[m][n] = f32x4{0.f, 0.f, 0.f, 0.f};

    // ---- segment B: steady-state invariant already holds ----
    for (int t = 0; t <= NT - 3; ++t) main_iter(t);
    {
      const int db = (NT - 2) & 1;
      RD_AF(0) RD_B(0, bgl) RD_B(1, bgh)
      stA(NT - 1, 1);
      Q_MFMA(0, 0, bgl)
      Q_MFMA(0, 2, bgh)
      RD_AF(1)
      Q_MFMA(4, 0, bgl)
      Q_MFMA(4, 2, bgh)
      WAITVM(0); SBAR();
    }
    {
      const int db = (NT - 1) & 1;
      RD_AF(0) RD_B(0, bgl) RD_B(1, bgh)
      Q_MFMA(0, 0, bgl)
      Q_MFMA(0, 2, bgh)
      RD_AF(1)
      Q_MFMA(4, 0, bgl)
      Q_MFMA(4, 2, bgh)
    }
    epiGQ(brow + 8192);
  } else {
    // tail t = NT-1, no staging
    {
      const int db = (NT - 1) & 1;
      RD_AF(0) RD_B(0, bgl) RD_B(1, bgh)
      Q_MFMA(0, 0, bgl)
      Q_MFMA(0, 2, bgh)
      RD_AF(1)
      Q_MFMA(4, 0, bgl)
      Q_MFMA(4, 2, bgh)
    }
    if constexpr (GQ) {
      epiGQ(brow);
    } else {
      float* outp = (float*)Cout;
#pragma unroll
      for (int m = 0; m < 8; m++) {
        const size_t rbase = (size_t)(brow + m * 32 + wr * 16 + lhi * 4);
#pragma unroll
        for (int r = 0; r < 4; r++) {
          const size_t ro = (rbase + r) * Nd;
#pragma unroll
          for (int n = 0; n < 4; n++)
            __builtin_nontemporal_store(acc[m][n][r] + bv[n],
                &outp[ro + cb + (n >> 1) * 128 + (n & 1) * 16 + l16]);
        }
      }
    }
  }
}

extern "C" void kernel_launch(void* const* d_in, const int* in_sizes, int n_in,
                              void* d_out, int out_size, void* d_ws, size_t ws_size,
                              hipStream_t stream) {
  const float* x      = (const float*)d_in[0];
  const float* w_fc   = (const float*)d_in[1];
  const float* b_fc   = (const float*)d_in[2];
  const float* w_proj = (const float*)d_in[3];
  const float* b_proj = (const float*)d_in[4];

  char* ws = (char*)d_ws;
  bf16* xq  = (bf16*)ws;  ws += (size_t)MROWS * EMB * 2;   // 32 MB
  bf16* wfq = (bf16*)ws;  ws += (size_t)HID * EMB * 2;     //  8 MB
  bf16* wpq = (bf16*)ws;  ws += (size_t)EMB * HID * 2;     //  8 MB
  bf16* hq  = (bf16*)ws;                                   // 128 MB

  quant32<<<(MROWS * EMB / 32 + 255) / 256, 256, 0, stream>>>(x, xq, MROWS * EMB / 32);
  quant32<<<(HID * EMB / 32 + 255) / 256, 256, 0, stream>>>(w_fc, wfq, HID * EMB / 32);
  quant32<<<(EMB * HID / 32 + 255) / 256, 256, 0, stream>>>(w_proj, wpq, EMB * HID / 32);

  // GEMM1: 512 blocks x 2 output tiles (spliced); GEMM2: 256 blocks x 1.
  gemm8<EMB, HID, true,  2><<<512, 512, 0, stream>>>(xq, wfq, b_fc, hq);
  gemm8<HID, EMB, false, 1><<<(MROWS / 256) * (EMB / 256), 512, 0, stream>>>(hq, wpq, b_proj, (float*)d_out);
}